// Round 1
// 853.425 us; speedup vs baseline: 1.0516x; 1.0516x over previous
//
#include <hip/hip_runtime.h>
#include <cstdint>
#include <cstddef>

#define D_    768
#define ROWS  32768      // row pairs (B*N)
#define MTOT  65536      // interleaved rows: 2i = x1_i, 2i+1 = x2_i
#define NMAIN 1536       // [ v (768) | c (768) ]
#define HID   192
#define KMLP  1536
#define NMLP  384

typedef __attribute__((ext_vector_type(4))) float f32x4;
typedef __attribute__((ext_vector_type(8))) short s16x8;

__device__ inline unsigned short f2bf(float f) {
  union { float f; uint32_t u; } c; c.f = f;
  uint32_t r = c.u + 0x7FFFu + ((c.u >> 16) & 1u);
  return (unsigned short)(r >> 16);
}
__device__ inline float bf2f(unsigned short h) {
  union { uint32_t u; float f; } c; c.u = ((uint32_t)h) << 16;
  return c.f;
}

__device__ inline void gld_lds16(const void* g, void* l) {
  __builtin_amdgcn_global_load_lds(
      (const __attribute__((address_space(1))) void*)g,
      (__attribute__((address_space(3))) void*)l, 16, 0, 0);
}

// ---- x1,x2 fp32 -> xb bf16, pair-interleaved [65536, 768]
__global__ void k_convert_x(const float* __restrict__ x1, const float* __restrict__ x2,
                            unsigned short* __restrict__ xb) {
  const int r = blockIdx.x;               // output row
  const int c = threadIdx.x * 4;
  const float* src = ((r & 1) ? x2 : x1) + (size_t)(r >> 1) * D_ + c;
  float4 v = *(const float4*)src;
  union { unsigned short u[4]; uint2 p; } o;
  o.u[0] = f2bf(v.x); o.u[1] = f2bf(v.y); o.u[2] = f2bf(v.z); o.u[3] = f2bf(v.w);
  *(uint2*)(xb + (size_t)r * D_ + c) = o.p;
}

// ---- weight conversions (see round-0 comments)
__global__ void k_convert_w(const float* __restrict__ Wq, const float* __restrict__ Wk,
                            const float* __restrict__ Wv, const float* __restrict__ W1,
                            unsigned short* __restrict__ Wqb, unsigned short* __restrict__ Wkb,
                            unsigned short* __restrict__ BtMain, unsigned short* __restrict__ BtMlp) {
  int idx = blockIdx.x * 256 + threadIdx.x;
  const int S = D_ * D_;
  if (idx < S) { Wqb[idx] = f2bf(Wq[idx]); return; }
  idx -= S;
  if (idx < S) { Wkb[idx] = f2bf(Wk[idx]); return; }
  idx -= S;
  if (idx < S) {
    int n = idx / D_, k = idx - n * D_;
    BtMain[idx] = f2bf(Wv[(size_t)k * D_ + n]);
    return;
  }
  idx -= S;
  if (idx < NMLP * KMLP) {
    int n = idx / KMLP, k = idx - n * KMLP;
    int cc = (n < HID) ? n : n - HID;
    int kk = (n < HID) ? k : ((k < D_) ? k + D_ : k - D_);
    BtMlp[idx] = f2bf(W1[(size_t)kk * HID + cc]);
  }
}

// ---- nk[j] = noise @ Wk ;  gn[a] = Wq[a][:] . nk  (fp32 throughout)
__global__ void k_nk(const float* __restrict__ noise, const float* __restrict__ Wk,
                     float* __restrict__ nk) {
  int j = blockIdx.x * 256 + threadIdx.x;
  if (j >= D_) return;
  float s = 0.f;
  for (int k = 0; k < D_; ++k) s += noise[k] * Wk[(size_t)k * D_ + j];
  nk[j] = s;
}
__global__ void k_gn(const float* __restrict__ Wq, const float* __restrict__ nk,
                     float* __restrict__ gn) {
  int a = blockIdx.x * 256 + threadIdx.x;
  if (a >= D_) return;
  float s = 0.f;
  for (int j = 0; j < D_; ++j) s += Wq[(size_t)a * D_ + j] * nk[j];
  gn[a] = s;
}

// ---- generic 128x128 bf16 GEMM (kept for the small G = Wq@Wk^T gemm)
template<int NTILES, bool SWIZ, int KK>
__launch_bounds__(256)
__global__ void k_gemm(const unsigned short* __restrict__ A,
                       const unsigned short* __restrict__ Bt,
                       unsigned short* __restrict__ C, int ldc) {
  __shared__ __align__(16) short As[128 * 32];
  __shared__ __align__(16) short Bs[128 * 32];
  const int tid = threadIdx.x;
  const int id = blockIdx.x;
  int mi, ni;
  if (SWIZ) {
    int t = id >> 3;
    mi = (id & 7) * ((gridDim.x / NTILES) >> 3) + t / NTILES;
    ni = t % NTILES;
  } else {
    mi = id / NTILES; ni = id % NTILES;
  }
  const int m0 = mi * 128, n0 = ni * 128;
  const int lane = tid & 63, wave = tid >> 6;
  const int wm = (wave >> 1) * 64, wn = (wave & 1) * 64;
  const int quad = lane >> 4, mr = lane & 15;
  f32x4 acc[4][4];
#pragma unroll
  for (int i = 0; i < 4; ++i)
#pragma unroll
    for (int j = 0; j < 4; ++j) acc[i][j] = (f32x4){0.f, 0.f, 0.f, 0.f};

  const int r = tid >> 2;
  const int q = (tid & 3) ^ ((r >> 1) & 3);
  const unsigned short* Ar0 = A + (size_t)(m0 + r) * KK + q * 8;
  const unsigned short* Ar1 = A + (size_t)(m0 + 64 + r) * KK + q * 8;
  const unsigned short* Br0 = Bt + (size_t)(n0 + r) * KK + q * 8;
  const unsigned short* Br1 = Bt + (size_t)(n0 + 64 + r) * KK + q * 8;

  int aoff[4], boff[4];
#pragma unroll
  for (int i = 0; i < 4; ++i) {
    int rl = wm + i * 16 + mr;
    aoff[i] = (rl * 4 + (quad ^ ((rl >> 1) & 3))) * 8;
    int nl = wn + i * 16 + mr;
    boff[i] = (nl * 4 + (quad ^ ((nl >> 1) & 3))) * 8;
  }

  for (int k0 = 0; k0 < KK; k0 += 32) {
    __syncthreads();
    gld_lds16(Ar0 + k0, &As[tid * 8]);
    gld_lds16(Ar1 + k0, &As[2048 + tid * 8]);
    gld_lds16(Br0 + k0, &Bs[tid * 8]);
    gld_lds16(Br1 + k0, &Bs[2048 + tid * 8]);
    __syncthreads();
    s16x8 a[4], b[4];
#pragma unroll
    for (int i = 0; i < 4; ++i) a[i] = *(const s16x8*)&As[aoff[i]];
#pragma unroll
    for (int j = 0; j < 4; ++j) b[j] = *(const s16x8*)&Bs[boff[j]];
#pragma unroll
    for (int i = 0; i < 4; ++i)
#pragma unroll
      for (int j = 0; j < 4; ++j)
        acc[i][j] = __builtin_amdgcn_mfma_f32_16x16x32_bf16(a[i], b[j], acc[i][j], 0, 0, 0);
  }
#pragma unroll
  for (int i = 0; i < 4; ++i) {
    int row = m0 + wm + i * 16 + quad * 4;
#pragma unroll
    for (int j = 0; j < 4; ++j) {
      int col = n0 + wn + j * 16 + mr;
#pragma unroll
      for (int t = 0; t < 4; ++t)
        C[(size_t)(row + t) * ldc + col] = f2bf(acc[i][j][t]);
    }
  }
}

// ---- main GEMM, 256x256 tile, 8-phase counted-vmcnt pipeline (T2+T3+T4+T5).
// A = xb [65536, 768], Bt = BtMain [1536, 768], C = vc [65536, 1536] bf16.
// 512 threads = 8 waves (2M x 4N), per-wave output 128x64.
// LDS: 2 slots x { A[2 ksub][256][32 sw] | B[2 ksub][256][32 sw] } = 128 KiB.
// Per K-tile (BK=64): 4 phases of 16 MFMA, split by (m-half, k-slice):
//   P1: s0,m0-3 (8 ds_read + stage A' s0)   P2: s0,m4-7 (4 ds + stage B' s0, vmcnt(4))
//   P3: s1,m0-3 (8 ds + stage A' s1)        P4: s1,m4-7 (4 ds + stage B' s1, vmcnt(4))
// Refill always targets the idle slot (computed last tile) -> race-free by the
// per-phase double-barrier; vmcnt(4) guarantees exactly the parts the next two
// phases read have landed, while keeping 4 loads in flight (never drains).
__launch_bounds__(512, 2)
__global__ void k_gemm256(const unsigned short* __restrict__ A,
                          const unsigned short* __restrict__ Bt,
                          unsigned short* __restrict__ C) {
  extern __shared__ __align__(16) short lds[];
  const int tid = threadIdx.x;
  const int id = blockIdx.x;
  const int xcd = id & 7, tt = id >> 3;      // 1536 blocks, 192/XCD, same-m grouped
  const int mi = xcd * 32 + tt / 6;
  const int ni = tt % 6;
  const int m0 = mi * 256, n0 = ni * 256;
  const int lane = tid & 63, wave = tid >> 6;
  const int WM = (wave >> 2) * 128, WN = (wave & 3) * 64;
  const int quad = lane >> 4, mr = lane & 15;

  f32x4 acc[8][4];
#pragma unroll
  for (int i = 0; i < 8; ++i)
#pragma unroll
    for (int j = 0; j < 4; ++j) acc[i][j] = (f32x4){0.f, 0.f, 0.f, 0.f};

  // staging: thread tid stages chunk g = l*512+tid of each 16KB part;
  // g -> (row r = g>>2, chunk q = g&3), source pre-swizzled so LDS stays linear.
  const int r0 = tid >> 2;
  const int q0 = ((tid & 3) ^ ((r0 >> 1) & 3)) * 8;
  const unsigned short* a0 = A + (size_t)(m0 + r0) * D_ + q0;
  const unsigned short* a1 = A + (size_t)(m0 + 128 + r0) * D_ + q0;   // (r+128)>>1 &3 == r>>1 &3
  const unsigned short* b0 = Bt + (size_t)(n0 + r0) * D_ + q0;
  const unsigned short* b1 = Bt + (size_t)(n0 + 128 + r0) * D_ + q0;
  const int ld0 = tid * 8, ld1 = 4096 + tid * 8;

#define STAGE_A(PO, KT, S) do { \
    gld_lds16(a0 + (KT) * 64 + (S) * 32, &lds[(PO) * 32768 + (S) * 8192 + ld0]); \
    gld_lds16(a1 + (KT) * 64 + (S) * 32, &lds[(PO) * 32768 + (S) * 8192 + ld1]); } while (0)
#define STAGE_B(PO, KT, S) do { \
    gld_lds16(b0 + (KT) * 64 + (S) * 32, &lds[(PO) * 32768 + 16384 + (S) * 8192 + ld0]); \
    gld_lds16(b1 + (KT) * 64 + (S) * 32, &lds[(PO) * 32768 + 16384 + (S) * 8192 + ld1]); } while (0)

  // fragment read offsets (shorts); swizzle chunk reduces to quad ^ ((mr>>1)&3)
  const int qa = (quad ^ ((mr >> 1) & 3)) * 8;
  int aoff[8], boff[4];
#pragma unroll
  for (int i = 0; i < 8; ++i) aoff[i] = (WM + i * 16 + mr) * 32 + qa;
#pragma unroll
  for (int j = 0; j < 4; ++j) boff[j] = (WN + j * 16 + mr) * 32 + qa;

  // prologue: tile 0 -> slot 0; wait for the s0 parts only (counted).
  STAGE_A(0, 0, 0); STAGE_B(0, 0, 0); STAGE_A(0, 0, 1); STAGE_B(0, 0, 1);
  asm volatile("s_waitcnt vmcnt(4)" ::: "memory");
  __builtin_amdgcn_s_barrier();

#pragma unroll
  for (int kt = 0; kt < 12; ++kt) {
    const int so = (kt & 1) * 32768;   // compute slot (shorts)
    const int po = (kt & 1) ^ 1;       // refill slot
    s16x8 aF[4], bF[4];

    // ---------- P1: ksub 0, m-frags 0-3 ----------
#pragma unroll
    for (int i = 0; i < 4; ++i) aF[i] = *(const s16x8*)&lds[so + aoff[i]];
#pragma unroll
    for (int j = 0; j < 4; ++j) bF[j] = *(const s16x8*)&lds[so + 16384 + boff[j]];
    if (kt < 11) STAGE_A(po, kt + 1, 0);
    __builtin_amdgcn_s_barrier();
    asm volatile("s_waitcnt lgkmcnt(0)" ::: "memory");
    __builtin_amdgcn_s_setprio(1);
#pragma unroll
    for (int i = 0; i < 4; ++i)
#pragma unroll
      for (int j = 0; j < 4; ++j)
        acc[i][j] = __builtin_amdgcn_mfma_f32_16x16x32_bf16(aF[i], bF[j], acc[i][j], 0, 0, 0);
    __builtin_amdgcn_s_setprio(0);
    __builtin_amdgcn_s_barrier();

    // ---------- P2: ksub 0, m-frags 4-7 ----------
#pragma unroll
    for (int i = 0; i < 4; ++i) aF[i] = *(const s16x8*)&lds[so + aoff[4 + i]];
    if (kt < 11) STAGE_B(po, kt + 1, 0);
    __builtin_amdgcn_s_barrier();
    asm volatile("s_waitcnt lgkmcnt(0)" ::: "memory");
    __builtin_amdgcn_s_setprio(1);
#pragma unroll
    for (int i = 0; i < 4; ++i)
#pragma unroll
      for (int j = 0; j < 4; ++j)
        acc[4 + i][j] = __builtin_amdgcn_mfma_f32_16x16x32_bf16(aF[i], bF[j], acc[4 + i][j], 0, 0, 0);
    __builtin_amdgcn_s_setprio(0);
    if (kt < 11) asm volatile("s_waitcnt vmcnt(4)" ::: "memory");  // s1 parts of this tile landed
    else         asm volatile("s_waitcnt vmcnt(0)" ::: "memory");
    __builtin_amdgcn_s_barrier();

    // ---------- P3: ksub 1, m-frags 0-3 ----------
#pragma unroll
    for (int i = 0; i < 4; ++i) aF[i] = *(const s16x8*)&lds[so + 8192 + aoff[i]];
#pragma unroll
    for (int j = 0; j < 4; ++j) bF[j] = *(const s16x8*)&lds[so + 16384 + 8192 + boff[j]];
    if (kt < 11) STAGE_A(po, kt + 1, 1);
    __builtin_amdgcn_s_barrier();
    asm volatile("s_waitcnt lgkmcnt(0)" ::: "memory");
    __builtin_amdgcn_s_setprio(1);
#pragma unroll
    for (int i = 0; i < 4; ++i)
#pragma unroll
      for (int j = 0; j < 4; ++j)
        acc[i][j] = __builtin_amdgcn_mfma_f32_16x16x32_bf16(aF[i], bF[j], acc[i][j], 0, 0, 0);
    __builtin_amdgcn_s_setprio(0);
    __builtin_amdgcn_s_barrier();

    // ---------- P4: ksub 1, m-frags 4-7 ----------
#pragma unroll
    for (int i = 0; i < 4; ++i) aF[i] = *(const s16x8*)&lds[so + 8192 + aoff[4 + i]];
    if (kt < 11) STAGE_B(po, kt + 1, 1);
    __builtin_amdgcn_s_barrier();
    asm volatile("s_waitcnt lgkmcnt(0)" ::: "memory");
    __builtin_amdgcn_s_setprio(1);
#pragma unroll
    for (int i = 0; i < 4; ++i)
#pragma unroll
      for (int j = 0; j < 4; ++j)
        acc[4 + i][j] = __builtin_amdgcn_mfma_f32_16x16x32_bf16(aF[i], bF[j], acc[4 + i][j], 0, 0, 0);
    __builtin_amdgcn_s_setprio(0);
    if (kt < 11) asm volatile("s_waitcnt vmcnt(4)" ::: "memory");  // next tile's s0 parts landed
    else         asm volatile("s_waitcnt vmcnt(0)" ::: "memory");
    __builtin_amdgcn_s_barrier();
  }
#undef STAGE_A
#undef STAGE_B

  // epilogue
#pragma unroll
  for (int i = 0; i < 8; ++i) {
    const int row = m0 + WM + i * 16 + quad * 4;
#pragma unroll
    for (int j = 0; j < 4; ++j) {
      const int col = n0 + WN + j * 16 + mr;
#pragma unroll
      for (int v = 0; v < 4; ++v)
        C[(size_t)(row + v) * NMAIN + col] = f2bf(acc[i][j][v]);
    }
  }
}

// ---- MLP GEMM (both directions fused): A = xb viewed [32768,1536], Bt = BtMlp [384,1536]
__launch_bounds__(256)
__global__ void k_gemm_mlp(const unsigned short* __restrict__ A,
                           const unsigned short* __restrict__ Bt,
                           const float* __restrict__ b1, const float* __restrict__ W2,
                           float* __restrict__ rel) {
  __shared__ __align__(16) short As[128 * 32];
  __shared__ __align__(16) short Bs[128 * 32];
  const int tid = threadIdx.x;
  const int id = blockIdx.x;            // 768 blocks
  int t0 = id >> 3;
  const int mi = (id & 7) * 32 + t0 / 3;
  const int ni = t0 % 3;
  const int m0 = mi * 128, n0 = ni * 128;
  const int lane = tid & 63, wave = tid >> 6;
  const int wm = (wave >> 1) * 64, wn = (wave & 1) * 64;
  const int quad = lane >> 4, mr = lane & 15;
  f32x4 acc[4][4];
#pragma unroll
  for (int i = 0; i < 4; ++i)
#pragma unroll
    for (int j = 0; j < 4; ++j) acc[i][j] = (f32x4){0.f, 0.f, 0.f, 0.f};

  const int r = tid >> 2;
  const int q = (tid & 3) ^ ((r >> 1) & 3);
  const unsigned short* Ar0 = A + (size_t)(m0 + r) * KMLP + q * 8;
  const unsigned short* Ar1 = A + (size_t)(m0 + 64 + r) * KMLP + q * 8;
  const unsigned short* Br0 = Bt + (size_t)(n0 + r) * KMLP + q * 8;
  const unsigned short* Br1 = Bt + (size_t)(n0 + 64 + r) * KMLP + q * 8;
  int aoff[4], boff[4];
#pragma unroll
  for (int i = 0; i < 4; ++i) {
    int rl = wm + i * 16 + mr;
    aoff[i] = (rl * 4 + (quad ^ ((rl >> 1) & 3))) * 8;
    int nl = wn + i * 16 + mr;
    boff[i] = (nl * 4 + (quad ^ ((nl >> 1) & 3))) * 8;
  }
  for (int k0 = 0; k0 < KMLP; k0 += 32) {
    __syncthreads();
    gld_lds16(Ar0 + k0, &As[tid * 8]);
    gld_lds16(Ar1 + k0, &As[2048 + tid * 8]);
    gld_lds16(Br0 + k0, &Bs[tid * 8]);
    gld_lds16(Br1 + k0, &Bs[2048 + tid * 8]);
    __syncthreads();
    s16x8 a[4], b[4];
#pragma unroll
    for (int i = 0; i < 4; ++i) a[i] = *(const s16x8*)&As[aoff[i]];
#pragma unroll
    for (int j = 0; j < 4; ++j) b[j] = *(const s16x8*)&Bs[boff[j]];
#pragma unroll
    for (int i = 0; i < 4; ++i)
#pragma unroll
      for (int j = 0; j < 4; ++j)
        acc[i][j] = __builtin_amdgcn_mfma_f32_16x16x32_bf16(a[i], b[j], acc[i][j], 0, 0, 0);
  }
  float part[2][4][4];
#pragma unroll
  for (int d = 0; d < 2; ++d)
#pragma unroll
    for (int i = 0; i < 4; ++i)
#pragma unroll
      for (int t = 0; t < 4; ++t) part[d][i][t] = 0.f;
#pragma unroll
  for (int j = 0; j < 4; ++j) {
    const int colb = n0 + wn + j * 16;        // wave-uniform
    const int dir = (colb >= HID) ? 1 : 0;
    const int cc = colb + mr - dir * HID;     // 0..191
    const float b1v = b1[cc];
    const float w2v = W2[cc];
#pragma unroll
    for (int i = 0; i < 4; ++i)
#pragma unroll
      for (int t = 0; t < 4; ++t) {
        float h = acc[i][j][t] + b1v;
        h = 0.5f * h * (1.f + erff(h * 0.70710678118654752f));
        part[dir][i][t] += h * w2v;
      }
  }
#pragma unroll
  for (int m = 1; m < 16; m <<= 1)
#pragma unroll
    for (int d = 0; d < 2; ++d)
#pragma unroll
      for (int i = 0; i < 4; ++i)
#pragma unroll
        for (int t = 0; t < 4; ++t)
          part[d][i][t] += __shfl_xor(part[d][i][t], m, 64);
  if (mr == 0) {
#pragma unroll
    for (int d = 0; d < 2; ++d)
#pragma unroll
      for (int i = 0; i < 4; ++i) {
        int p = m0 + wm + i * 16 + quad * 4;
#pragma unroll
        for (int t = 0; t < 4; ++t)
          atomicAdd(&rel[(size_t)d * ROWS + p + t], part[d][i][t]);
      }
  }
}

// ---- fusion: one wave per row-pair
__launch_bounds__(256)
__global__ void k_fuse(const float* __restrict__ x1, const float* __restrict__ x2,
                       const unsigned short* __restrict__ vc, const float* __restrict__ gn,
                       const float* __restrict__ rel, const float* __restrict__ b2,
                       float* __restrict__ y) {
  const int p = blockIdx.x * 4 + (threadIdx.x >> 6);
  const int lane = threadIdx.x & 63;
  const unsigned short* L1 = vc + (size_t)(2 * p) * NMAIN;
  const unsigned short* L2 = L1 + NMAIN;
  const float* X1 = x1 + (size_t)p * D_;
  const float* X2 = x2 + (size_t)p * D_;
  float d11 = 0.f, d12 = 0.f, d21 = 0.f, d22 = 0.f;
  for (int c = lane; c < 96; c += 64) {
    const int off = c * 8;
    s16x8 c1 = *(const s16x8*)(L1 + D_ + off);
    s16x8 c2 = *(const s16x8*)(L2 + D_ + off);
    union F8 { float4 v[2]; float f[8]; };
    F8 a1, a2, g;
    a1.v[0] = *(const float4*)(X1 + off); a1.v[1] = *(const float4*)(X1 + off + 4);
    a2.v[0] = *(const float4*)(X2 + off); a2.v[1] = *(const float4*)(X2 + off + 4);
    g.v[0]  = *(const float4*)(gn + off); g.v[1]  = *(const float4*)(gn + off + 4);
#pragma unroll
    for (int e = 0; e < 8; ++e) {
      float fc1 = bf2f(c1[e]), fc2 = bf2f(c2[e]);
      d11 += a1.f[e] * (fc1 + g.f[e]);
      d12 += a1.f[e] * fc2;
      d21 += a2.f[e] * fc1;
      d22 += a2.f[e] * (fc2 + g.f[e]);
    }
  }
#pragma unroll
  for (int m = 1; m < 64; m <<= 1) {
    d11 += __shfl_xor(d11, m, 64);
    d12 += __shfl_xor(d12, m, 64);
    d21 += __shfl_xor(d21, m, 64);
    d22 += __shfl_xor(d22, m, 64);
  }
  const float scale = 0.0360843918243516f;   // 768^-0.5
  const float b2v = b2[0];
  const float r1 = 1.f / (1.f + expf(-(rel[p] + b2v)));
  const float r2 = 1.f / (1.f + expf(-(rel[ROWS + p] + b2v)));
  const float ds1 = d11 * scale, dc1 = r1 * d12 * scale;
  const float ds2 = d22 * scale, dc2 = r2 * d21 * scale;
  const float ws1 = 1.f / (1.f + expf(dc1 - ds1)), wc1 = 1.f - ws1;
  const float ws2 = 1.f / (1.f + expf(dc2 - ds2)), wc2 = 1.f - ws2;
  float* Y1 = y + (size_t)p * D_;
  float* Y2 = y + (size_t)(ROWS + p) * D_;
  for (int c = lane; c < 96; c += 64) {
    const int off = c * 8;
    s16x8 v1 = *(const s16x8*)(L1 + off);
    s16x8 v2 = *(const s16x8*)(L2 + off);
    union F8 { float4 v[2]; float f[8]; };
    F8 a1, a2, o1, o2;
    a1.v[0] = *(const float4*)(X1 + off); a1.v[1] = *(const float4*)(X1 + off + 4);
    a2.v[0] = *(const float4*)(X2 + off); a2.v[1] = *(const float4*)(X2 + off + 4);
#pragma unroll
    for (int e = 0; e < 8; ++e) {
      float fv1 = bf2f(v1[e]), fv2 = bf2f(v2[e]);
      o1.f[e] = a1.f[e] + ws1 * fv1 + wc1 * fv2;
      o2.f[e] = a2.f[e] + ws2 * fv2 + wc2 * fv1;
    }
    *(float4*)(Y1 + off) = o1.v[0]; *(float4*)(Y1 + off + 4) = o1.v[1];
    *(float4*)(Y2 + off) = o2.v[0]; *(float4*)(Y2 + off + 4) = o2.v[1];
  }
}

extern "C" void kernel_launch(void* const* d_in, const int* in_sizes, int n_in,
                              void* d_out, int out_size, void* d_ws, size_t ws_size,
                              hipStream_t stream) {
  const float* x1 = (const float*)d_in[0];
  const float* x2 = (const float*)d_in[1];
  const float* Wq = (const float*)d_in[2];
  const float* Wk = (const float*)d_in[3];
  const float* Wv = (const float*)d_in[4];
  const float* noise = (const float*)d_in[5];
  const float* W1 = (const float*)d_in[6];
  const float* b1 = (const float*)d_in[7];
  const float* W2 = (const float*)d_in[8];
  const float* b2 = (const float*)d_in[9];
  float* y = (float*)d_out;

  char* ws = (char*)d_ws;
  size_t off = 0;
  auto alloc = [&](size_t bytes) {
    char* p = ws + off;
    off += (bytes + 255) & ~(size_t)255;
    return p;
  };
  unsigned short* xb     = (unsigned short*)alloc((size_t)MTOT * D_ * 2);     // 100.7 MB
  unsigned short* vc     = (unsigned short*)alloc((size_t)MTOT * NMAIN * 2);  // 201.3 MB
  unsigned short* BtMain = (unsigned short*)alloc((size_t)NMAIN * D_ * 2);    // v^T | G
  unsigned short* Wqb    = (unsigned short*)alloc((size_t)D_ * D_ * 2);
  unsigned short* Wkb    = (unsigned short*)alloc((size_t)D_ * D_ * 2);
  unsigned short* BtMlp  = (unsigned short*)alloc((size_t)NMLP * KMLP * 2);
  float* nk              = (float*)alloc((size_t)D_ * 4);
  float* gn              = (float*)alloc((size_t)D_ * 4);
  float* rel             = (float*)alloc((size_t)2 * ROWS * 4);

  static bool attr_set = false;
  if (!attr_set) {
    (void)hipFuncSetAttribute((const void*)k_gemm256,
                              hipFuncAttributeMaxDynamicSharedMemorySize, 131072);
    attr_set = true;
  }

  hipMemsetAsync(rel, 0, (size_t)2 * ROWS * 4, stream);

  k_convert_x<<<dim3(MTOT), 192, 0, stream>>>(x1, x2, xb);

  {
    int total = 3 * D_ * D_ + NMLP * KMLP;
    k_convert_w<<<dim3((total + 255) / 256), 256, 0, stream>>>(Wq, Wk, Wv, W1,
                                                               Wqb, Wkb, BtMain, BtMlp);
  }
  k_nk<<<dim3(3), 256, 0, stream>>>(noise, Wk, nk);
  k_gn<<<dim3(3), 256, 0, stream>>>(Wq, nk, gn);

  // G = Wq @ Wk^T (bf16) -> BtMain rows 768..1535
  k_gemm<6, false, D_><<<dim3(36), 256, 0, stream>>>(Wqb, Wkb, BtMain + (size_t)D_ * D_, D_);

  // main: vc = xb @ [Wv^T; G]^T  (256x256 tiles, 8-phase pipeline, XCD-swizzled)
  k_gemm256<<<dim3(1536), 512, 131072, stream>>>(xb, BtMain, vc);

  // MLP both dirs: rel logits
  k_gemm_mlp<<<dim3(768), 256, 0, stream>>>(xb, BtMlp, b1, W2, rel);

  // fusion
  k_fuse<<<dim3(ROWS / 4), 256, 0, stream>>>(x1, x2, vc, gn, rel, b2, y);
}

// Round 2
// 807.201 us; speedup vs baseline: 1.1118x; 1.0573x over previous
//
#include <hip/hip_runtime.h>
#include <cstdint>
#include <cstddef>

#define D_    768
#define ROWS  32768      // row pairs (B*N)
#define MTOT  65536      // interleaved rows: 2i = x1_i, 2i+1 = x2_i
#define HID   192
#define KMLP  1536
#define NMLP  384

typedef __attribute__((ext_vector_type(4))) float f32x4;
typedef __attribute__((ext_vector_type(8))) short s16x8;

__device__ inline unsigned short f2bf(float f) {
  union { float f; uint32_t u; } c; c.f = f;
  uint32_t r = c.u + 0x7FFFu + ((c.u >> 16) & 1u);
  return (unsigned short)(r >> 16);
}
__device__ inline float bf2f(unsigned short h) {
  union { uint32_t u; float f; } c; c.u = ((uint32_t)h) << 16;
  return c.f;
}

__device__ inline void gld_lds16(const void* g, void* l) {
  __builtin_amdgcn_global_load_lds(
      (const __attribute__((address_space(1))) void*)g,
      (__attribute__((address_space(3))) void*)l, 16, 0, 0);
}

// ---- x1,x2 fp32 -> xb bf16, pair-interleaved [65536, 768]
__global__ void k_convert_x(const float* __restrict__ x1, const float* __restrict__ x2,
                            unsigned short* __restrict__ xb) {
  const int r = blockIdx.x;               // output row
  const int c = threadIdx.x * 4;
  const float* src = ((r & 1) ? x2 : x1) + (size_t)(r >> 1) * D_ + c;
  float4 v = *(const float4*)src;
  union { unsigned short u[4]; uint2 p; } o;
  o.u[0] = f2bf(v.x); o.u[1] = f2bf(v.y); o.u[2] = f2bf(v.z); o.u[3] = f2bf(v.w);
  *(uint2*)(xb + (size_t)r * D_ + c) = o.p;
}

// ---- weight conversions
__global__ void k_convert_w(const float* __restrict__ Wq, const float* __restrict__ Wk,
                            const float* __restrict__ Wv, const float* __restrict__ W1,
                            unsigned short* __restrict__ Wqb, unsigned short* __restrict__ Wkb,
                            unsigned short* __restrict__ BtMain, unsigned short* __restrict__ BtMlp) {
  int idx = blockIdx.x * 256 + threadIdx.x;
  const int S = D_ * D_;
  if (idx < S) { Wqb[idx] = f2bf(Wq[idx]); return; }
  idx -= S;
  if (idx < S) { Wkb[idx] = f2bf(Wk[idx]); return; }
  idx -= S;
  if (idx < S) {
    int n = idx / D_, k = idx - n * D_;
    BtMain[idx] = f2bf(Wv[(size_t)k * D_ + n]);
    return;
  }
  idx -= S;
  if (idx < NMLP * KMLP) {
    int n = idx / KMLP, k = idx - n * KMLP;
    int cc = (n < HID) ? n : n - HID;
    int kk = (n < HID) ? k : ((k < D_) ? k + D_ : k - D_);
    BtMlp[idx] = f2bf(W1[(size_t)kk * HID + cc]);
  }
}

// ---- nk[j] = noise @ Wk ;  gn[a] = Wq[a][:] . nk  (fp32 throughout)
__global__ void k_nk(const float* __restrict__ noise, const float* __restrict__ Wk,
                     float* __restrict__ nk) {
  int j = blockIdx.x * 256 + threadIdx.x;
  if (j >= D_) return;
  float s = 0.f;
  for (int k = 0; k < D_; ++k) s += noise[k] * Wk[(size_t)k * D_ + j];
  nk[j] = s;
}
__global__ void k_gn(const float* __restrict__ Wq, const float* __restrict__ nk,
                     float* __restrict__ gn) {
  int a = blockIdx.x * 256 + threadIdx.x;
  if (a >= D_) return;
  float s = 0.f;
  for (int j = 0; j < D_; ++j) s += Wq[(size_t)a * D_ + j] * nk[j];
  gn[a] = s;
}

// ---- generic 128x128 bf16 GEMM (kept for the small G = Wq@Wk^T gemm)
template<int NTILES, bool SWIZ, int KK>
__launch_bounds__(256)
__global__ void k_gemm(const unsigned short* __restrict__ A,
                       const unsigned short* __restrict__ Bt,
                       unsigned short* __restrict__ C, int ldc) {
  __shared__ __align__(16) short As[128 * 32];
  __shared__ __align__(16) short Bs[128 * 32];
  const int tid = threadIdx.x;
  const int id = blockIdx.x;
  int mi, ni;
  if (SWIZ) {
    int t = id >> 3;
    mi = (id & 7) * ((gridDim.x / NTILES) >> 3) + t / NTILES;
    ni = t % NTILES;
  } else {
    mi = id / NTILES; ni = id % NTILES;
  }
  const int m0 = mi * 128, n0 = ni * 128;
  const int lane = tid & 63, wave = tid >> 6;
  const int wm = (wave >> 1) * 64, wn = (wave & 1) * 64;
  const int quad = lane >> 4, mr = lane & 15;
  f32x4 acc[4][4];
#pragma unroll
  for (int i = 0; i < 4; ++i)
#pragma unroll
    for (int j = 0; j < 4; ++j) acc[i][j] = (f32x4){0.f, 0.f, 0.f, 0.f};

  const int r = tid >> 2;
  const int q = (tid & 3) ^ ((r >> 1) & 3);
  const unsigned short* Ar0 = A + (size_t)(m0 + r) * KK + q * 8;
  const unsigned short* Ar1 = A + (size_t)(m0 + 64 + r) * KK + q * 8;
  const unsigned short* Br0 = Bt + (size_t)(n0 + r) * KK + q * 8;
  const unsigned short* Br1 = Bt + (size_t)(n0 + 64 + r) * KK + q * 8;

  int aoff[4], boff[4];
#pragma unroll
  for (int i = 0; i < 4; ++i) {
    int rl = wm + i * 16 + mr;
    aoff[i] = (rl * 4 + (quad ^ ((rl >> 1) & 3))) * 8;
    int nl = wn + i * 16 + mr;
    boff[i] = (nl * 4 + (quad ^ ((nl >> 1) & 3))) * 8;
  }

  for (int k0 = 0; k0 < KK; k0 += 32) {
    __syncthreads();
    gld_lds16(Ar0 + k0, &As[tid * 8]);
    gld_lds16(Ar1 + k0, &As[2048 + tid * 8]);
    gld_lds16(Br0 + k0, &Bs[tid * 8]);
    gld_lds16(Br1 + k0, &Bs[2048 + tid * 8]);
    __syncthreads();
    s16x8 a[4], b[4];
#pragma unroll
    for (int i = 0; i < 4; ++i) a[i] = *(const s16x8*)&As[aoff[i]];
#pragma unroll
    for (int j = 0; j < 4; ++j) b[j] = *(const s16x8*)&Bs[boff[j]];
#pragma unroll
    for (int i = 0; i < 4; ++i)
#pragma unroll
      for (int j = 0; j < 4; ++j)
        acc[i][j] = __builtin_amdgcn_mfma_f32_16x16x32_bf16(a[i], b[j], acc[i][j], 0, 0, 0);
  }
#pragma unroll
  for (int i = 0; i < 4; ++i) {
    int row = m0 + wm + i * 16 + quad * 4;
#pragma unroll
    for (int j = 0; j < 4; ++j) {
      int col = n0 + wn + j * 16 + mr;
#pragma unroll
      for (int t = 0; t < 4; ++t)
        C[(size_t)(row + t) * ldc + col] = f2bf(acc[i][j][t]);
    }
  }
}

// ---- main GEMM, 256x256 tile, BK=32, 4-slot LDS ring, 3-slot-ahead prefetch.
// A = xb [65536, 768], Bt = BtMain [1536, 768] ([Wv^T | G]).
// Blocks with ni < 3 (v-half): write C = vc [65536, 768] bf16.
// Blocks with ni >= 3 (c-half): NO C write; compute partial dot products
//   d11 = x_even.(c_even+gn), d12 = x_even.c_odd, d21 = x_odd.c_even,
//   d22 = x_odd.(c_odd+gn)  and atomicAdd into dts[4][32768].
// Pipeline per slot s (24 slots of K=32): 2 phases x 16 MFMA.
//   Ph_a: ds_read aF[0-3],bF[0-3] (8) | stage A(slot s+3) | bar | lgkm0 | MFMA | bar
//   Ph_b: ds_read aF[4-7]       (4) | stage B(slot s+3) | bar | lgkm0 | MFMA |
//         vmcnt(8) [waits slot s+1, issued 6 phases ago] | bar
__launch_bounds__(512, 2)
__global__ void k_gemm256(const unsigned short* __restrict__ A,
                          const unsigned short* __restrict__ Bt,
                          unsigned short* __restrict__ C,
                          const float* __restrict__ gn,
                          float* __restrict__ dts) {
  extern __shared__ __align__(16) short lds[];
  const int tid = threadIdx.x;
  const int id = blockIdx.x;
  const int xcd = id & 7, tt = id >> 3;      // 1536 blocks, 192/XCD, same-m grouped
  const int mi = xcd * 32 + tt / 6;
  const int ni = tt % 6;
  const int m0 = mi * 256, n0 = ni * 256;
  const int lane = tid & 63, wave = tid >> 6;
  const int WM = (wave >> 2) * 128, WN = (wave & 3) * 64;
  const int quad = lane >> 4, mr = lane & 15;

  f32x4 acc[8][4];
#pragma unroll
  for (int i = 0; i < 8; ++i)
#pragma unroll
    for (int j = 0; j < 4; ++j) acc[i][j] = (f32x4){0.f, 0.f, 0.f, 0.f};

  // staging: thread tid -> row r0 = tid>>2 (0..127), lds chunk qt = tid&3;
  // global chunk pre-swizzled: q = qt ^ ((r0>>1)&3). LDS stays linear.
  const int r0 = tid >> 2;
  const int qg = ((tid & 3) ^ ((r0 >> 1) & 3)) * 8;
  const unsigned short* a0 = A + (size_t)(m0 + r0) * D_ + qg;
  const unsigned short* a1 = A + (size_t)(m0 + 128 + r0) * D_ + qg;  // ((r0+128)>>1)&3 == ((r0>>1))&3
  const unsigned short* b0 = Bt + (size_t)(n0 + r0) * D_ + qg;
  const unsigned short* b1 = Bt + (size_t)(n0 + 128 + r0) * D_ + qg;
  const int ld0 = tid * 8;

  // slot layout (shorts): slot*16384 + { A[256][32] | B[256][32] at +8192 }
#define STAGE_A(SL, S) do { \
    gld_lds16(a0 + (S) * 32, &lds[(SL) * 16384 + ld0]); \
    gld_lds16(a1 + (S) * 32, &lds[(SL) * 16384 + 4096 + ld0]); } while (0)
#define STAGE_B(SL, S) do { \
    gld_lds16(b0 + (S) * 32, &lds[(SL) * 16384 + 8192 + ld0]); \
    gld_lds16(b1 + (S) * 32, &lds[(SL) * 16384 + 8192 + 4096 + ld0]); } while (0)

  const int qa = (quad ^ ((mr >> 1) & 3)) * 8;  // note: swizzle term dep. only on row bits 1..2
  int aoff[8], boff[4];
#pragma unroll
  for (int i = 0; i < 8; ++i) {
    int rl = WM + i * 16 + mr;
    aoff[i] = (rl * 4 + (quad ^ ((rl >> 1) & 3))) * 8;
  }
#pragma unroll
  for (int j = 0; j < 4; ++j) {
    int nl = WN + j * 16 + mr;
    boff[j] = (nl * 4 + (quad ^ ((nl >> 1) & 3))) * 8;
  }
  (void)qa;

  // prologue: stage slots 0,1,2 ; wait for slot 0 (8 newest still in flight)
  STAGE_A(0, 0); STAGE_B(0, 0);
  STAGE_A(1, 1); STAGE_B(1, 1);
  STAGE_A(2, 2); STAGE_B(2, 2);
  asm volatile("s_waitcnt vmcnt(8)" ::: "memory");
  __builtin_amdgcn_s_barrier();

#pragma unroll
  for (int s = 0; s < 24; ++s) {
    const int sb = (s & 3) * 16384;        // compute slot
    const int pb = (s + 3) & 3;            // prefetch slot (= slot computed at s-1)
    s16x8 aF[4], bF[4];

    // ---------- Ph_a : m-frags 0-3 ----------
#pragma unroll
    for (int i = 0; i < 4; ++i) aF[i] = *(const s16x8*)&lds[sb + aoff[i]];
#pragma unroll
    for (int j = 0; j < 4; ++j) bF[j] = *(const s16x8*)&lds[sb + 8192 + boff[j]];
    if (s < 21) STAGE_A(pb, s + 3);
    __builtin_amdgcn_s_barrier();
    asm volatile("s_waitcnt lgkmcnt(0)" ::: "memory");
    __builtin_amdgcn_s_setprio(1);
#pragma unroll
    for (int i = 0; i < 4; ++i)
#pragma unroll
      for (int j = 0; j < 4; ++j)
        acc[i][j] = __builtin_amdgcn_mfma_f32_16x16x32_bf16(aF[i], bF[j], acc[i][j], 0, 0, 0);
    __builtin_amdgcn_s_setprio(0);
    __builtin_amdgcn_s_barrier();

    // ---------- Ph_b : m-frags 4-7 ----------
#pragma unroll
    for (int i = 0; i < 4; ++i) aF[i] = *(const s16x8*)&lds[sb + aoff[4 + i]];
    if (s < 21) STAGE_B(pb, s + 3);
    __builtin_amdgcn_s_barrier();
    asm volatile("s_waitcnt lgkmcnt(0)" ::: "memory");
    __builtin_amdgcn_s_setprio(1);
#pragma unroll
    for (int i = 0; i < 4; ++i)
#pragma unroll
      for (int j = 0; j < 4; ++j)
        acc[4 + i][j] = __builtin_amdgcn_mfma_f32_16x16x32_bf16(aF[i], bF[j], acc[4 + i][j], 0, 0, 0);
    __builtin_amdgcn_s_setprio(0);
    if (s < 21)      asm volatile("s_waitcnt vmcnt(8)" ::: "memory");
    else if (s == 21) asm volatile("s_waitcnt vmcnt(4)" ::: "memory");
    else if (s == 22) asm volatile("s_waitcnt vmcnt(0)" ::: "memory");
    __builtin_amdgcn_s_barrier();
  }
#undef STAGE_A
#undef STAGE_B

  if (ni < 3) {
    // v-half epilogue: write vc (ldc = 768)
#pragma unroll
    for (int i = 0; i < 8; ++i) {
      const int row = m0 + WM + i * 16 + quad * 4;
#pragma unroll
      for (int j = 0; j < 4; ++j) {
        const int col = n0 + WN + j * 16 + mr;
#pragma unroll
        for (int v = 0; v < 4; ++v)
          C[(size_t)(row + v) * D_ + col] = f2bf(acc[i][j][v]);
      }
    }
  } else {
    // c-half epilogue: partial dots, no C write
    const int cc0 = n0 - D_;
#pragma unroll
    for (int i = 0; i < 8; ++i) {
      const int rb = m0 + WM + i * 16 + quad * 4;   // even row (pairs rb/2, rb/2+1)
      float xv[4][4], gv[4];
#pragma unroll
      for (int j = 0; j < 4; ++j) {
        const int cc = cc0 + WN + j * 16 + mr;
        gv[j] = gn[cc];
#pragma unroll
        for (int t = 0; t < 4; ++t)
          xv[t][j] = bf2f(A[(size_t)(rb + t) * D_ + cc]);
      }
      float d[2][4];
#pragma unroll
      for (int tp = 0; tp < 2; ++tp)
#pragma unroll
        for (int k = 0; k < 4; ++k) d[tp][k] = 0.f;
#pragma unroll
      for (int tp = 0; tp < 2; ++tp)
#pragma unroll
        for (int j = 0; j < 4; ++j) {
          const float c1 = acc[i][j][tp * 2], c2 = acc[i][j][tp * 2 + 1];
          const float a1v = xv[tp * 2][j], a2v = xv[tp * 2 + 1][j];
          d[tp][0] += a1v * (c1 + gv[j]);
          d[tp][1] += a1v * c2;
          d[tp][2] += a2v * c1;
          d[tp][3] += a2v * (c2 + gv[j]);
        }
#pragma unroll
      for (int m = 1; m < 16; m <<= 1)
#pragma unroll
        for (int tp = 0; tp < 2; ++tp)
#pragma unroll
          for (int k = 0; k < 4; ++k)
            d[tp][k] += __shfl_xor(d[tp][k], m, 64);
      if (mr == 0) {
#pragma unroll
        for (int tp = 0; tp < 2; ++tp) {
          const int p = (rb >> 1) + tp;
#pragma unroll
          for (int k = 0; k < 4; ++k)
            atomicAdd(&dts[(size_t)k * ROWS + p], d[tp][k]);
        }
      }
    }
  }
}

// ---- MLP GEMM (both directions fused): A = xb viewed [32768,1536], Bt = BtMlp [384,1536]
__launch_bounds__(256)
__global__ void k_gemm_mlp(const unsigned short* __restrict__ A,
                           const unsigned short* __restrict__ Bt,
                           const float* __restrict__ b1, const float* __restrict__ W2,
                           float* __restrict__ rel) {
  __shared__ __align__(16) short As[128 * 32];
  __shared__ __align__(16) short Bs[128 * 32];
  const int tid = threadIdx.x;
  const int id = blockIdx.x;            // 768 blocks
  int t0 = id >> 3;
  const int mi = (id & 7) * 32 + t0 / 3;
  const int ni = t0 % 3;
  const int m0 = mi * 128, n0 = ni * 128;
  const int lane = tid & 63, wave = tid >> 6;
  const int wm = (wave >> 1) * 64, wn = (wave & 1) * 64;
  const int quad = lane >> 4, mr = lane & 15;
  f32x4 acc[4][4];
#pragma unroll
  for (int i = 0; i < 4; ++i)
#pragma unroll
    for (int j = 0; j < 4; ++j) acc[i][j] = (f32x4){0.f, 0.f, 0.f, 0.f};

  const int r = tid >> 2;
  const int q = (tid & 3) ^ ((r >> 1) & 3);
  const unsigned short* Ar0 = A + (size_t)(m0 + r) * KMLP + q * 8;
  const unsigned short* Ar1 = A + (size_t)(m0 + 64 + r) * KMLP + q * 8;
  const unsigned short* Br0 = Bt + (size_t)(n0 + r) * KMLP + q * 8;
  const unsigned short* Br1 = Bt + (size_t)(n0 + 64 + r) * KMLP + q * 8;
  int aoff[4], boff[4];
#pragma unroll
  for (int i = 0; i < 4; ++i) {
    int rl = wm + i * 16 + mr;
    aoff[i] = (rl * 4 + (quad ^ ((rl >> 1) & 3))) * 8;
    int nl = wn + i * 16 + mr;
    boff[i] = (nl * 4 + (quad ^ ((nl >> 1) & 3))) * 8;
  }
  for (int k0 = 0; k0 < KMLP; k0 += 32) {
    __syncthreads();
    gld_lds16(Ar0 + k0, &As[tid * 8]);
    gld_lds16(Ar1 + k0, &As[2048 + tid * 8]);
    gld_lds16(Br0 + k0, &Bs[tid * 8]);
    gld_lds16(Br1 + k0, &Bs[2048 + tid * 8]);
    __syncthreads();
    s16x8 a[4], b[4];
#pragma unroll
    for (int i = 0; i < 4; ++i) a[i] = *(const s16x8*)&As[aoff[i]];
#pragma unroll
    for (int j = 0; j < 4; ++j) b[j] = *(const s16x8*)&Bs[boff[j]];
#pragma unroll
    for (int i = 0; i < 4; ++i)
#pragma unroll
      for (int j = 0; j < 4; ++j)
        acc[i][j] = __builtin_amdgcn_mfma_f32_16x16x32_bf16(a[i], b[j], acc[i][j], 0, 0, 0);
  }
  float part[2][4][4];
#pragma unroll
  for (int d = 0; d < 2; ++d)
#pragma unroll
    for (int i = 0; i < 4; ++i)
#pragma unroll
      for (int t = 0; t < 4; ++t) part[d][i][t] = 0.f;
#pragma unroll
  for (int j = 0; j < 4; ++j) {
    const int colb = n0 + wn + j * 16;        // wave-uniform
    const int dir = (colb >= HID) ? 1 : 0;
    const int cc = colb + mr - dir * HID;     // 0..191
    const float b1v = b1[cc];
    const float w2v = W2[cc];
#pragma unroll
    for (int i = 0; i < 4; ++i)
#pragma unroll
      for (int t = 0; t < 4; ++t) {
        float h = acc[i][j][t] + b1v;
        h = 0.5f * h * (1.f + erff(h * 0.70710678118654752f));
        part[dir][i][t] += h * w2v;
      }
  }
#pragma unroll
  for (int m = 1; m < 16; m <<= 1)
#pragma unroll
    for (int d = 0; d < 2; ++d)
#pragma unroll
      for (int i = 0; i < 4; ++i)
#pragma unroll
        for (int t = 0; t < 4; ++t)
          part[d][i][t] += __shfl_xor(part[d][i][t], m, 64);
  if (mr == 0) {
#pragma unroll
    for (int d = 0; d < 2; ++d)
#pragma unroll
      for (int i = 0; i < 4; ++i) {
        int p = m0 + wm + i * 16 + quad * 4;
#pragma unroll
        for (int t = 0; t < 4; ++t)
          atomicAdd(&rel[(size_t)d * ROWS + p + t], part[d][i][t]);
      }
  }
}

// ---- fusion: one wave per row-pair (dots precomputed by k_gemm256)
__launch_bounds__(256)
__global__ void k_fuse(const float* __restrict__ x1, const float* __restrict__ x2,
                       const unsigned short* __restrict__ vc,
                       const float* __restrict__ dts, const float* __restrict__ rel,
                       const float* __restrict__ b2, float* __restrict__ y) {
  const int p = blockIdx.x * 4 + (threadIdx.x >> 6);
  const int lane = threadIdx.x & 63;
  const unsigned short* L1 = vc + (size_t)(2 * p) * D_;
  const unsigned short* L2 = L1 + D_;
  const float* X1 = x1 + (size_t)p * D_;
  const float* X2 = x2 + (size_t)p * D_;
  const float scale = 0.0360843918243516f;   // 768^-0.5
  const float b2v = b2[0];
  const float d11 = dts[p], d12 = dts[ROWS + p];
  const float d21 = dts[2 * ROWS + p], d22 = dts[3 * ROWS + p];
  const float r1 = 1.f / (1.f + expf(-(rel[p] + b2v)));
  const float r2 = 1.f / (1.f + expf(-(rel[ROWS + p] + b2v)));
  const float ds1 = d11 * scale, dc1 = r1 * d12 * scale;
  const float ds2 = d22 * scale, dc2 = r2 * d21 * scale;
  const float ws1 = 1.f / (1.f + expf(dc1 - ds1)), wc1 = 1.f - ws1;
  const float ws2 = 1.f / (1.f + expf(dc2 - ds2)), wc2 = 1.f - ws2;
  float* Y1 = y + (size_t)p * D_;
  float* Y2 = y + (size_t)(ROWS + p) * D_;
  for (int c = lane; c < 96; c += 64) {
    const int off = c * 8;
    s16x8 v1 = *(const s16x8*)(L1 + off);
    s16x8 v2 = *(const s16x8*)(L2 + off);
    union F8 { float4 v[2]; float f[8]; };
    F8 a1, a2, o1, o2;
    a1.v[0] = *(const float4*)(X1 + off); a1.v[1] = *(const float4*)(X1 + off + 4);
    a2.v[0] = *(const float4*)(X2 + off); a2.v[1] = *(const float4*)(X2 + off + 4);
#pragma unroll
    for (int e = 0; e < 8; ++e) {
      float fv1 = bf2f(v1[e]), fv2 = bf2f(v2[e]);
      o1.f[e] = a1.f[e] + ws1 * fv1 + wc1 * fv2;
      o2.f[e] = a2.f[e] + ws2 * fv2 + wc2 * fv1;
    }
    *(float4*)(Y1 + off) = o1.v[0]; *(float4*)(Y1 + off + 4) = o1.v[1];
    *(float4*)(Y2 + off) = o2.v[0]; *(float4*)(Y2 + off + 4) = o2.v[1];
  }
}

extern "C" void kernel_launch(void* const* d_in, const int* in_sizes, int n_in,
                              void* d_out, int out_size, void* d_ws, size_t ws_size,
                              hipStream_t stream) {
  const float* x1 = (const float*)d_in[0];
  const float* x2 = (const float*)d_in[1];
  const float* Wq = (const float*)d_in[2];
  const float* Wk = (const float*)d_in[3];
  const float* Wv = (const float*)d_in[4];
  const float* noise = (const float*)d_in[5];
  const float* W1 = (const float*)d_in[6];
  const float* b1 = (const float*)d_in[7];
  const float* W2 = (const float*)d_in[8];
  const float* b2 = (const float*)d_in[9];
  float* y = (float*)d_out;

  char* ws = (char*)d_ws;
  size_t off = 0;
  auto alloc = [&](size_t bytes) {
    char* p = ws + off;
    off += (bytes + 255) & ~(size_t)255;
    return p;
  };
  unsigned short* xb     = (unsigned short*)alloc((size_t)MTOT * D_ * 2);       // 100.7 MB
  unsigned short* vc     = (unsigned short*)alloc((size_t)MTOT * D_ * 2);       // 100.7 MB (v-half only)
  unsigned short* BtMain = (unsigned short*)alloc((size_t)2 * D_ * D_ * 2);     // [Wv^T | G]
  unsigned short* Wqb    = (unsigned short*)alloc((size_t)D_ * D_ * 2);
  unsigned short* Wkb    = (unsigned short*)alloc((size_t)D_ * D_ * 2);
  unsigned short* BtMlp  = (unsigned short*)alloc((size_t)NMLP * KMLP * 2);
  float* nk              = (float*)alloc((size_t)D_ * 4);
  float* gn              = (float*)alloc((size_t)D_ * 4);
  float* rel             = (float*)alloc((size_t)2 * ROWS * 4);
  float* dts             = (float*)alloc((size_t)4 * ROWS * 4);

  static bool attr_set = false;
  if (!attr_set) {
    (void)hipFuncSetAttribute((const void*)k_gemm256,
                              hipFuncAttributeMaxDynamicSharedMemorySize, 131072);
    attr_set = true;
  }

  hipMemsetAsync(rel, 0, (size_t)2 * ROWS * 4, stream);
  hipMemsetAsync(dts, 0, (size_t)4 * ROWS * 4, stream);

  k_convert_x<<<dim3(MTOT), 192, 0, stream>>>(x1, x2, xb);

  {
    int total = 3 * D_ * D_ + NMLP * KMLP;
    k_convert_w<<<dim3((total + 255) / 256), 256, 0, stream>>>(Wq, Wk, Wv, W1,
                                                               Wqb, Wkb, BtMain, BtMlp);
  }
  k_nk<<<dim3(3), 256, 0, stream>>>(noise, Wk, nk);
  k_gn<<<dim3(3), 256, 0, stream>>>(Wq, nk, gn);

  // G = Wq @ Wk^T (bf16) -> BtMain rows 768..1535
  k_gemm<6, false, D_><<<dim3(36), 256, 0, stream>>>(Wqb, Wkb, BtMain + (size_t)D_ * D_, D_);

  // main: v-half -> vc writes; c-half -> in-epilogue dots
  k_gemm256<<<dim3(1536), 512, 131072, stream>>>(xb, BtMain, vc, gn, dts);

  // MLP both dirs: rel logits
  k_gemm_mlp<<<dim3(768), 256, 0, stream>>>(xb, BtMlp, b1, W2, rel);

  // fusion
  k_fuse<<<dim3(ROWS / 4), 256, 0, stream>>>(x1, x2, vc, dts, rel, b2, y);
}